// Round 4
// baseline (309.334 us; speedup 1.0000x reference)
//
#include <hip/hip_runtime.h>
#include <hip/hip_bf16.h>

#define N_ROWS 2048
#define K_DIM  8192
#define MARGIN 0.2f

typedef __attribute__((ext_vector_type(4))) float f32x4;
typedef __bf16 bf16x8 __attribute__((ext_vector_type(8)));

// ---------------- workspace layout (split path) ----------------
// [0]        : float acc
// [4]        : unsigned counter
// [64]       : inv_c (2048 f32)
// [64+8192]  : inv_a (2048 f32)
// [32768]    : Cbf (2048*8192 u16)  33.55 MB
// [+33.55MB] : Abf (2048*8192 u16)  33.55 MB
// [67141632] : simPart bf16, nsplit * 2048*2048*2 B (8.39 MB each)

__device__ inline unsigned short f2bf_rne(float f) {
    unsigned int u = __float_as_uint(f);
    unsigned int r = (u + 0x7fffu + ((u >> 16) & 1u)) >> 16;
    return (unsigned short)r;
}
__device__ inline float bf2f(unsigned short u) {
    return __uint_as_float(((unsigned int)u) << 16);
}

// One block per (row, matrix): 1/max(||row||,eps) + bf16 copy of raw row.
// Block (0,0) also zeroes the accumulator + ticket counter for this launch.
__global__ __launch_bounds__(256) void norm_convert(
    const float* __restrict__ c_in, const float* __restrict__ a_in,
    unsigned short* __restrict__ Cbf, unsigned short* __restrict__ Abf,
    float* __restrict__ invc, float* __restrict__ inva,
    float* __restrict__ acc, unsigned int* __restrict__ counter) {
    const int row = blockIdx.x;
    const int which = blockIdx.y;
    if (row == 0 && which == 0 && threadIdx.x == 0) { acc[0] = 0.f; counter[0] = 0u; }
    const float* src = (which == 0 ? c_in : a_in) + (size_t)row * K_DIM;
    unsigned short* dst = (which == 0 ? Cbf : Abf) + (size_t)row * K_DIM;
    float* invp = (which == 0 ? invc : inva);

    const float4* src4 = (const float4*)src;
    float s = 0.f;
#pragma unroll
    for (int i = 0; i < 8; ++i) {
        float4 v = src4[threadIdx.x + i * 256];
        s += v.x * v.x + v.y * v.y + v.z * v.z + v.w * v.w;
        ushort4 o;
        o.x = f2bf_rne(v.x);
        o.y = f2bf_rne(v.y);
        o.z = f2bf_rne(v.z);
        o.w = f2bf_rne(v.w);
        ((ushort4*)dst)[threadIdx.x + i * 256] = o;   // store early, frees regs
    }
#pragma unroll
    for (int off = 32; off; off >>= 1) s += __shfl_down(s, off);
    __shared__ float red[4];
    if ((threadIdx.x & 63) == 0) red[threadIdx.x >> 6] = s;
    __syncthreads();
    if (threadIdx.x == 0) {
        float t = red[0] + red[1] + red[2] + red[3];
        invp[row] = 1.0f / fmaxf(sqrtf(t), 1e-12f);
    }
}

// Split-K partial GEMM: 128x128 tile, BK=64, 4 waves, grid (256, nsplit).
// Writes the raw partial Gram tile as bf16 to simPart[kc].
__global__ __launch_bounds__(256) void gemm_partial(
    const unsigned short* __restrict__ Cbf, const unsigned short* __restrict__ Abf,
    unsigned short* __restrict__ simPart, int kchunk) {
    __shared__ unsigned short ldsA[128 * 64];
    __shared__ unsigned short ldsB[128 * 64];

    const int b = blockIdx.x;
    const int swz = (b & 7) * 32 + (b >> 3);   // XCD-contiguous chunks
    const int bx = swz & 15;
    const int by = swz >> 4;
    const int kc = blockIdx.y;

    const int tid  = threadIdx.x;
    const int lane = tid & 63;
    const int w    = tid >> 6;
    const int wr   = w >> 1;
    const int wc   = w & 1;

    f32x4 acc[4][4];
#pragma unroll
    for (int i = 0; i < 4; ++i)
#pragma unroll
        for (int j = 0; j < 4; ++j) acc[i][j] = (f32x4)0.f;

    const int lrow = lane >> 3;
    const int lcol = (lane & 7) * 8;

    const unsigned short* gA = Cbf + (size_t)(by * 128) * K_DIM;
    const unsigned short* gB = Abf + (size_t)(bx * 128) * K_DIM;
    const int kbeg = kc * kchunk;
    const int kend = kbeg + kchunk;

    for (int k0 = kbeg; k0 < kend; k0 += 64) {
        __syncthreads();
#pragma unroll
        for (int r = 0; r < 4; ++r) {
            const int chunk = r * 4 + w;
            const int row = chunk * 8 + lrow;
            const unsigned short* src = gA + (size_t)row * K_DIM + k0 + lcol;
            __builtin_amdgcn_global_load_lds(
                (const __attribute__((address_space(1))) unsigned int*)src,
                (__attribute__((address_space(3))) unsigned int*)&ldsA[chunk * 512],
                16, 0, 0);
        }
#pragma unroll
        for (int r = 0; r < 4; ++r) {
            const int chunk = r * 4 + w;
            const int row = chunk * 8 + lrow;
            const unsigned short* src = gB + (size_t)row * K_DIM + k0 + lcol;
            __builtin_amdgcn_global_load_lds(
                (const __attribute__((address_space(1))) unsigned int*)src,
                (__attribute__((address_space(3))) unsigned int*)&ldsB[chunk * 512],
                16, 0, 0);
        }
        __syncthreads();

#pragma unroll
        for (int kk = 0; kk < 64; kk += 32) {
            bf16x8 af[4], bfr[4];
            const int krd = kk + (lane >> 4) * 8;
            const int rsel = lane & 15;
#pragma unroll
            for (int mi = 0; mi < 4; ++mi)
                af[mi] = *(const bf16x8*)&ldsA[(wr * 64 + mi * 16 + rsel) * 64 + krd];
#pragma unroll
            for (int ni = 0; ni < 4; ++ni)
                bfr[ni] = *(const bf16x8*)&ldsB[(wc * 64 + ni * 16 + rsel) * 64 + krd];
#pragma unroll
            for (int mi = 0; mi < 4; ++mi)
#pragma unroll
                for (int ni = 0; ni < 4; ++ni)
                    acc[mi][ni] = __builtin_amdgcn_mfma_f32_16x16x32_bf16(
                        af[mi], bfr[ni], acc[mi][ni], 0, 0, 0);
        }
    }

    // write bf16 partial tile
    unsigned short* outp = simPart + ((size_t)kc << 22);   // kc * 2048*2048
    const int row0 = by * 128 + wr * 64;
    const int col0 = bx * 128 + wc * 64;
#pragma unroll
    for (int mi = 0; mi < 4; ++mi) {
#pragma unroll
        for (int ni = 0; ni < 4; ++ni) {
            const int col = col0 + ni * 16 + (lane & 15);
            const int rbase = row0 + mi * 16 + (lane >> 4) * 4;
#pragma unroll
            for (int r = 0; r < 4; ++r)
                outp[(size_t)(rbase + r) * N_ROWS + col] = f2bf_rne(acc[mi][ni][r]);
        }
    }
}

// One block per row: sum partials, scale by inv-norms, hinge/diag, reduce.
// Last block (ticket) writes the final scalar.
__global__ __launch_bounds__(256) void epilogue_loss(
    const unsigned short* __restrict__ simPart, int nsplit,
    const float* __restrict__ invc, const float* __restrict__ inva,
    float* __restrict__ acc, unsigned int* __restrict__ counter,
    float* __restrict__ out) {
    const int row = blockIdx.x;
    const int j0 = threadIdx.x * 8;
    float s[8];
#pragma unroll
    for (int e = 0; e < 8; ++e) s[e] = 0.f;
    for (int p = 0; p < nsplit; ++p) {
        const unsigned short* base = simPart + (((size_t)p) << 22) + (size_t)row * N_ROWS + j0;
        ushort4 u0 = ((const ushort4*)base)[0];
        ushort4 u1 = ((const ushort4*)base)[1];
        s[0] += bf2f(u0.x); s[1] += bf2f(u0.y); s[2] += bf2f(u0.z); s[3] += bf2f(u0.w);
        s[4] += bf2f(u1.x); s[5] += bf2f(u1.y); s[6] += bf2f(u1.z); s[7] += bf2f(u1.w);
    }
    const float ic = invc[row];
    float local = 0.f;
#pragma unroll
    for (int e = 0; e < 8; ++e) {
        const int j = j0 + e;
        const float sim = s[e] * ic * inva[j];
        const float d2 = fmaxf(2.f - 2.f * sim, 0.f);
        if (j == row) {
            local += d2;
        } else {
            float t = fmaxf(MARGIN - sqrtf(d2), 0.f);
            local += t * t;
        }
    }
#pragma unroll
    for (int off = 32; off; off >>= 1) local += __shfl_down(local, off);
    __shared__ float red[4];
    if ((threadIdx.x & 63) == 0) red[threadIdx.x >> 6] = local;
    __syncthreads();
    if (threadIdx.x == 0) {
        atomicAdd(acc, red[0] + red[1] + red[2] + red[3]);
        __threadfence();
        unsigned int old = atomicAdd(counter, 1u);
        if (old == gridDim.x - 1) {
            float total = atomicAdd(acc, 0.0f);   // atomic read of final sum
            out[0] = total / (2.0f * N_ROWS);
        }
    }
}

// ---------- fallback (round-1 verified): fused epilogue, grid 256 ----------
__global__ __launch_bounds__(256) void gemm_loss(
    const unsigned short* __restrict__ Cbf, const unsigned short* __restrict__ Abf,
    const float* __restrict__ invc, const float* __restrict__ inva,
    float* __restrict__ acc_out) {
    __shared__ unsigned short ldsA[128 * 64];
    __shared__ unsigned short ldsB[128 * 64];
    const int b = blockIdx.x;
    const int swz = (b & 7) * 32 + (b >> 3);
    const int bx = swz & 15;
    const int by = swz >> 4;
    const int tid  = threadIdx.x;
    const int lane = tid & 63;
    const int w    = tid >> 6;
    const int wr   = w >> 1;
    const int wc   = w & 1;
    f32x4 acc[4][4];
#pragma unroll
    for (int i = 0; i < 4; ++i)
#pragma unroll
        for (int j = 0; j < 4; ++j) acc[i][j] = (f32x4)0.f;
    const int lrow = lane >> 3;
    const int lcol = (lane & 7) * 8;
    const unsigned short* gA = Cbf + (size_t)(by * 128) * K_DIM;
    const unsigned short* gB = Abf + (size_t)(bx * 128) * K_DIM;
    for (int k0 = 0; k0 < K_DIM; k0 += 64) {
        __syncthreads();
#pragma unroll
        for (int r = 0; r < 4; ++r) {
            const int chunk = r * 4 + w;
            const int row = chunk * 8 + lrow;
            __builtin_amdgcn_global_load_lds(
                (const __attribute__((address_space(1))) unsigned int*)(gA + (size_t)row * K_DIM + k0 + lcol),
                (__attribute__((address_space(3))) unsigned int*)&ldsA[chunk * 512], 16, 0, 0);
        }
#pragma unroll
        for (int r = 0; r < 4; ++r) {
            const int chunk = r * 4 + w;
            const int row = chunk * 8 + lrow;
            __builtin_amdgcn_global_load_lds(
                (const __attribute__((address_space(1))) unsigned int*)(gB + (size_t)row * K_DIM + k0 + lcol),
                (__attribute__((address_space(3))) unsigned int*)&ldsB[chunk * 512], 16, 0, 0);
        }
        __syncthreads();
#pragma unroll
        for (int kk = 0; kk < 64; kk += 32) {
            bf16x8 af[4], bfr[4];
            const int krd = kk + (lane >> 4) * 8;
            const int rsel = lane & 15;
#pragma unroll
            for (int mi = 0; mi < 4; ++mi)
                af[mi] = *(const bf16x8*)&ldsA[(wr * 64 + mi * 16 + rsel) * 64 + krd];
#pragma unroll
            for (int ni = 0; ni < 4; ++ni)
                bfr[ni] = *(const bf16x8*)&ldsB[(wc * 64 + ni * 16 + rsel) * 64 + krd];
#pragma unroll
            for (int mi = 0; mi < 4; ++mi)
#pragma unroll
                for (int ni = 0; ni < 4; ++ni)
                    acc[mi][ni] = __builtin_amdgcn_mfma_f32_16x16x32_bf16(
                        af[mi], bfr[ni], acc[mi][ni], 0, 0, 0);
        }
    }
    const int row0 = by * 128 + wr * 64;
    const int col0 = bx * 128 + wc * 64;
    float ia[4];
#pragma unroll
    for (int ni = 0; ni < 4; ++ni) ia[ni] = inva[col0 + ni * 16 + (lane & 15)];
    float ic[4][4];
#pragma unroll
    for (int mi = 0; mi < 4; ++mi)
#pragma unroll
        for (int r = 0; r < 4; ++r)
            ic[mi][r] = invc[row0 + mi * 16 + (lane >> 4) * 4 + r];
    float local = 0.f;
#pragma unroll
    for (int mi = 0; mi < 4; ++mi) {
#pragma unroll
        for (int ni = 0; ni < 4; ++ni) {
            const int col = col0 + ni * 16 + (lane & 15);
            const int rbase = row0 + mi * 16 + (lane >> 4) * 4;
#pragma unroll
            for (int r = 0; r < 4; ++r) {
                const float sim = acc[mi][ni][r] * ic[mi][r] * ia[ni];
                const float d2 = fmaxf(2.f - 2.f * sim, 0.f);
                if (rbase + r == col) {
                    local += d2;
                } else {
                    float t = fmaxf(MARGIN - sqrtf(d2), 0.f);
                    local += t * t;
                }
            }
        }
    }
#pragma unroll
    for (int off = 32; off; off >>= 1) local += __shfl_down(local, off);
    __shared__ float red[4];
    if (lane == 0) red[w] = local;
    __syncthreads();
    if (tid == 0) atomicAdd(acc_out, red[0] + red[1] + red[2] + red[3]);
}

__global__ void finalize(const float* __restrict__ acc, float* __restrict__ out) {
    if (threadIdx.x == 0 && blockIdx.x == 0)
        out[0] = acc[0] / (2.0f * N_ROWS);
}

extern "C" void kernel_launch(void* const* d_in, const int* in_sizes, int n_in,
                              void* d_out, int out_size, void* d_ws, size_t ws_size,
                              hipStream_t stream) {
    const float* c_in = (const float*)d_in[0];
    const float* a_in = (const float*)d_in[1];
    float* out = (float*)d_out;

    char* ws = (char*)d_ws;
    float* accp = (float*)ws;
    unsigned int* counter = (unsigned int*)(ws + 4);
    float* invc = (float*)(ws + 64);
    float* inva = (float*)(ws + 64 + 2048 * 4);
    unsigned short* Cbf = (unsigned short*)(ws + 32768);
    unsigned short* Abf = Cbf + (size_t)N_ROWS * K_DIM;
    unsigned short* simPart = (unsigned short*)(ws + 32768 + 2 * (size_t)N_ROWS * K_DIM * 2);

    const size_t baseNeed = 32768 + 2 * (size_t)N_ROWS * K_DIM * 2;      // 67.1 MB
    const size_t partBytes = (size_t)N_ROWS * N_ROWS * 2;                 // 8.39 MB

    int nsplit = 0;
    if (ws_size >= baseNeed + 4 * partBytes) nsplit = 4;
    else if (ws_size >= baseNeed + 2 * partBytes) nsplit = 2;
    else if (ws_size >= baseNeed + 1 * partBytes) nsplit = 1;

    norm_convert<<<dim3(N_ROWS, 2), 256, 0, stream>>>(c_in, a_in, Cbf, Abf,
                                                      invc, inva, accp, counter);
    if (nsplit > 0) {
        gemm_partial<<<dim3(256, nsplit), 256, 0, stream>>>(Cbf, Abf, simPart,
                                                            K_DIM / nsplit);
        epilogue_loss<<<dim3(N_ROWS), 256, 0, stream>>>(simPart, nsplit, invc, inva,
                                                        accp, counter, out);
    } else {
        gemm_loss<<<dim3(256), 256, 0, stream>>>(Cbf, Abf, invc, inva, accp);
        finalize<<<1, 64, 0, stream>>>(accp, out);
    }
}

// Round 5
// 289.172 us; speedup vs baseline: 1.0697x; 1.0697x over previous
//
#include <hip/hip_runtime.h>
#include <hip/hip_bf16.h>

#define N_ROWS 2048
#define K_DIM  8192
#define MARGIN 0.2f

typedef __attribute__((ext_vector_type(4))) float f32x4;
typedef __bf16 bf16x8 __attribute__((ext_vector_type(8)));

#define AS1 __attribute__((address_space(1)))
#define AS3 __attribute__((address_space(3)))

// ---------------- workspace layout (split path) ----------------
// [0]        : float acc
// [4]        : unsigned counter
// [64]       : inv_c (2048 f32)
// [64+8192]  : inv_a (2048 f32)
// [32768]    : Cbf (2048*8192 u16)  33.55 MB
// [+33.55MB] : Abf (2048*8192 u16)  33.55 MB
// [67141632] : simPart bf16, nsplit * 2048*2048*2 B (8.39 MB each)

__device__ inline unsigned short f2bf_rne(float f) {
    unsigned int u = __float_as_uint(f);
    unsigned int r = (u + 0x7fffu + ((u >> 16) & 1u)) >> 16;
    return (unsigned short)r;
}
__device__ inline float bf2f(unsigned short u) {
    return __uint_as_float(((unsigned int)u) << 16);
}

// One block per (row, matrix): 1/max(||row||,eps) + bf16 copy of raw row.
__global__ __launch_bounds__(256) void norm_convert(
    const float* __restrict__ c_in, const float* __restrict__ a_in,
    unsigned short* __restrict__ Cbf, unsigned short* __restrict__ Abf,
    float* __restrict__ invc, float* __restrict__ inva,
    float* __restrict__ acc, unsigned int* __restrict__ counter) {
    const int row = blockIdx.x;
    const int which = blockIdx.y;
    if (row == 0 && which == 0 && threadIdx.x == 0) { acc[0] = 0.f; counter[0] = 0u; }
    const float* src = (which == 0 ? c_in : a_in) + (size_t)row * K_DIM;
    unsigned short* dst = (which == 0 ? Cbf : Abf) + (size_t)row * K_DIM;
    float* invp = (which == 0 ? invc : inva);

    const float4* src4 = (const float4*)src;
    float s = 0.f;
#pragma unroll
    for (int i = 0; i < 8; ++i) {
        float4 v = src4[threadIdx.x + i * 256];
        s += v.x * v.x + v.y * v.y + v.z * v.z + v.w * v.w;
        ushort4 o;
        o.x = f2bf_rne(v.x);
        o.y = f2bf_rne(v.y);
        o.z = f2bf_rne(v.z);
        o.w = f2bf_rne(v.w);
        ((ushort4*)dst)[threadIdx.x + i * 256] = o;
    }
#pragma unroll
    for (int off = 32; off; off >>= 1) s += __shfl_down(s, off);
    __shared__ float red[4];
    if ((threadIdx.x & 63) == 0) red[threadIdx.x >> 6] = s;
    __syncthreads();
    if (threadIdx.x == 0) {
        float t = red[0] + red[1] + red[2] + red[3];
        invp[row] = 1.0f / fmaxf(sqrtf(t), 1e-12f);
    }
}

// ---------------- 8-phase 256x256 split-K GEMM ----------------
// 512 threads = 8 waves (2M x 4N). Per-wave output 128x64.
// LDS: 8 slots x 16KB (A/B half-tiles, 2 K-tiles resident). Counted vmcnt.

#define BAR __builtin_amdgcn_s_barrier()
#define VMCNT4 asm volatile("s_waitcnt vmcnt(4)" ::: "memory")
#define VMCNT8 asm volatile("s_waitcnt vmcnt(8)" ::: "memory")

// stage one 128x64 half-tile (16KB) into LDS slot: 2 x global_load_lds dwordx4
#define STAGE(gbase, halfrowbase, kt, slot) do {                                   \
    const unsigned short* _s = (gbase) + (size_t)((halfrowbase) + srow) * K_DIM    \
                               + (size_t)(K0 + (kt) * 64 + scol);                  \
    __builtin_amdgcn_global_load_lds((const AS1 unsigned int*)_s,                  \
        (AS3 unsigned int*)&lds[(slot) * 8192 + tid * 8], 16, 0, 0);               \
    __builtin_amdgcn_global_load_lds((const AS1 unsigned int*)(_s + (size_t)64 * K_DIM), \
        (AS3 unsigned int*)&lds[(slot) * 8192 + 4096 + tid * 8], 16, 0, 0);        \
} while (0)

// read 4 A-fragment rows (mi = mh*4 .. +4), both k-slices
#define READ_A(p, mh) do {                                                         \
    const int _sb = ((p) * 4 + wm) * 8192;                                         \
    _Pragma("unroll") for (int r = 0; r < 4; ++r) {                                \
        const int _row = (mh) * 64 + r * 16 + rsel;                                \
        a_r[r][0] = *(const bf16x8*)&lds[_sb + _row * 64 + khi];                    \
        a_r[r][1] = *(const bf16x8*)&lds[_sb + _row * 64 + 32 + khi];              \
    } } while (0)

// read 2 B-fragment cols (ni = nh*2 .. +2), both k-slices
#define READ_B(p, nh) do {                                                         \
    const int _sb = ((p) * 4 + 2 + (wn >> 1)) * 8192;                              \
    _Pragma("unroll") for (int q = 0; q < 2; ++q) {                                \
        const int _ni = (nh) * 2 + q;                                              \
        const int _row = (wn & 1) * 64 + _ni * 16 + rsel;                          \
        b_r[_ni][0] = *(const bf16x8*)&lds[_sb + _row * 64 + khi];                 \
        b_r[_ni][1] = *(const bf16x8*)&lds[_sb + _row * 64 + 32 + khi];            \
    } } while (0)

// 16 MFMA = one C-quadrant over K=64
#define MFMA_Q(mh, nh) do {                                                        \
    __builtin_amdgcn_s_setprio(1);                                                 \
    _Pragma("unroll") for (int r = 0; r < 4; ++r)                                  \
    _Pragma("unroll") for (int q = 0; q < 2; ++q) {                                \
        const int _mi = (mh) * 4 + r, _ni = (nh) * 2 + q;                          \
        acc[_mi][_ni] = __builtin_amdgcn_mfma_f32_16x16x32_bf16(                   \
            a_r[r][0], b_r[_ni][0], acc[_mi][_ni], 0, 0, 0);                       \
        acc[_mi][_ni] = __builtin_amdgcn_mfma_f32_16x16x32_bf16(                   \
            a_r[r][1], b_r[_ni][1], acc[_mi][_ni], 0, 0, 0);                       \
    }                                                                              \
    __builtin_amdgcn_s_setprio(0);                                                 \
} while (0)

__global__ __launch_bounds__(512, 2) void gemm_partial8(
    const unsigned short* __restrict__ Cbf, const unsigned short* __restrict__ Abf,
    unsigned short* __restrict__ simPart, int kchunk) {
    __shared__ unsigned short lds[65536];   // 8 slots x 8192 elems = 128 KB

    const int b = blockIdx.x;               // 0..63
    const int swz = (b & 7) * 8 + (b >> 3); // XCD-contiguous
    const int bm = swz >> 3, bn = swz & 7;
    const int kc = blockIdx.y;
    const int K0 = kc * kchunk;
    const int NT = kchunk >> 6;             // K-tiles (even)

    const int tid = threadIdx.x;
    const int lane = tid & 63;
    const int w = tid >> 6;
    const int wm = w >> 2, wn = w & 3;
    const int rsel = lane & 15;
    const int khi = (lane >> 4) * 8;
    const int srow = tid >> 3;              // staging row 0..63
    const int scol = (tid & 7) * 8;         // staging col

    const unsigned short* gA = Cbf + (size_t)(bm * 256) * K_DIM;
    const unsigned short* gB = Abf + (size_t)(bn * 256) * K_DIM;

    f32x4 acc[8][4];
#pragma unroll
    for (int i = 0; i < 8; ++i)
#pragma unroll
        for (int j = 0; j < 4; ++j) acc[i][j] = (f32x4)0.f;

    bf16x8 a_r[4][2], b_r[4][2];

    // prologue: K-tile 0 -> slots 0-3, K-tile 1 -> slots 4-7
    STAGE(gA, 0, 0, 0); STAGE(gA, 128, 0, 1); STAGE(gB, 0, 0, 2); STAGE(gB, 128, 0, 3);
    STAGE(gA, 0, 1, 4); STAGE(gA, 128, 1, 5); STAGE(gB, 0, 1, 6); STAGE(gB, 128, 1, 7);
    VMCNT8;   // slots 0-3 landed; 4-7 still in flight
    BAR;

    for (int it = 0; it < NT / 2; ++it) {
        const int t1 = 2 * it + 1;
        const int e2 = (2 * it + 2 < NT) ? 2 * it + 2 : NT - 1;  // clamped: staged, never read
        const int e3 = (2 * it + 3 < NT) ? 2 * it + 3 : NT - 1;
        // ---- K-tile 2it (slots 0-3) ----
        // ph1
        READ_A(0, 0); READ_B(0, 0);
        STAGE(gA, 0, t1, 4);
        BAR; MFMA_Q(0, 0); BAR;
        // ph2
        READ_B(0, 1);
        STAGE(gA, 128, t1, 5);
        BAR; MFMA_Q(0, 1); BAR;
        // ph3
        READ_A(0, 1);
        STAGE(gB, 0, e2, 2);
        BAR; MFMA_Q(1, 1); BAR;
        // ph4
        STAGE(gB, 128, e2, 3);
        VMCNT4;           // slots 4-7 guaranteed resident for phases 5-8
        BAR; MFMA_Q(1, 0); BAR;
        // ---- K-tile 2it+1 (slots 4-7) ----
        // ph5
        READ_A(1, 0); READ_B(1, 0);
        STAGE(gA, 0, e2, 0);
        BAR; MFMA_Q(0, 0); BAR;
        // ph6
        READ_B(1, 1);
        STAGE(gA, 128, e2, 1);
        BAR; MFMA_Q(0, 1); BAR;
        // ph7
        READ_A(1, 1);
        STAGE(gB, 0, e3, 6);
        BAR; MFMA_Q(1, 1); BAR;
        // ph8
        STAGE(gB, 128, e3, 7);
        VMCNT4;           // slots 0-3 guaranteed resident for next iter
        BAR; MFMA_Q(1, 0); BAR;
    }

    // write bf16 partial tile
    unsigned short* outp = simPart + ((size_t)kc << 22);
    const int row0 = bm * 256 + wm * 128;
    const int col0 = bn * 256 + wn * 64;
#pragma unroll
    for (int mi = 0; mi < 8; ++mi) {
#pragma unroll
        for (int ni = 0; ni < 4; ++ni) {
            const int gc = col0 + ni * 16 + (lane & 15);
            const int gr0 = row0 + mi * 16 + (lane >> 4) * 4;
#pragma unroll
            for (int r = 0; r < 4; ++r)
                outp[(size_t)(gr0 + r) * N_ROWS + gc] = f2bf_rne(acc[mi][ni][r]);
        }
    }
}

// One block per row: sum partials, scale by inv-norms, hinge/diag, reduce.
__global__ __launch_bounds__(256) void epilogue_loss(
    const unsigned short* __restrict__ simPart, int nsplit,
    const float* __restrict__ invc, const float* __restrict__ inva,
    float* __restrict__ acc, unsigned int* __restrict__ counter,
    float* __restrict__ out) {
    const int row = blockIdx.x;
    const int j0 = threadIdx.x * 8;
    float s[8];
#pragma unroll
    for (int e = 0; e < 8; ++e) s[e] = 0.f;
    for (int p = 0; p < nsplit; ++p) {
        const unsigned short* base = simPart + (((size_t)p) << 22) + (size_t)row * N_ROWS + j0;
        ushort4 u0 = ((const ushort4*)base)[0];
        ushort4 u1 = ((const ushort4*)base)[1];
        s[0] += bf2f(u0.x); s[1] += bf2f(u0.y); s[2] += bf2f(u0.z); s[3] += bf2f(u0.w);
        s[4] += bf2f(u1.x); s[5] += bf2f(u1.y); s[6] += bf2f(u1.z); s[7] += bf2f(u1.w);
    }
    const float ic = invc[row];
    float local = 0.f;
#pragma unroll
    for (int e = 0; e < 8; ++e) {
        const int j = j0 + e;
        const float sim = s[e] * ic * inva[j];
        const float d2 = fmaxf(2.f - 2.f * sim, 0.f);
        if (j == row) {
            local += d2;
        } else {
            float t = fmaxf(MARGIN - sqrtf(d2), 0.f);
            local += t * t;
        }
    }
#pragma unroll
    for (int off = 32; off; off >>= 1) local += __shfl_down(local, off);
    __shared__ float red[4];
    if ((threadIdx.x & 63) == 0) red[threadIdx.x >> 6] = local;
    __syncthreads();
    if (threadIdx.x == 0) {
        atomicAdd(acc, red[0] + red[1] + red[2] + red[3]);
        __threadfence();
        unsigned int old = atomicAdd(counter, 1u);
        if (old == gridDim.x - 1) {
            float total = atomicAdd(acc, 0.0f);
            out[0] = total / (2.0f * N_ROWS);
        }
    }
}

// ---------- fallback (round-1 verified): fused epilogue, grid 256 ----------
__global__ __launch_bounds__(256) void gemm_loss(
    const unsigned short* __restrict__ Cbf, const unsigned short* __restrict__ Abf,
    const float* __restrict__ invc, const float* __restrict__ inva,
    float* __restrict__ acc_out) {
    __shared__ unsigned short ldsA[128 * 64];
    __shared__ unsigned short ldsB[128 * 64];
    const int b = blockIdx.x;
    const int swz = (b & 7) * 32 + (b >> 3);
    const int bx = swz & 15;
    const int by = swz >> 4;
    const int tid  = threadIdx.x;
    const int lane = tid & 63;
    const int w    = tid >> 6;
    const int wr   = w >> 1;
    const int wc   = w & 1;
    f32x4 acc[4][4];
#pragma unroll
    for (int i = 0; i < 4; ++i)
#pragma unroll
        for (int j = 0; j < 4; ++j) acc[i][j] = (f32x4)0.f;
    const int lrow = lane >> 3;
    const int lcol = (lane & 7) * 8;
    const unsigned short* gA = Cbf + (size_t)(by * 128) * K_DIM;
    const unsigned short* gB = Abf + (size_t)(bx * 128) * K_DIM;
    for (int k0 = 0; k0 < K_DIM; k0 += 64) {
        __syncthreads();
#pragma unroll
        for (int r = 0; r < 4; ++r) {
            const int chunk = r * 4 + w;
            const int row = chunk * 8 + lrow;
            __builtin_amdgcn_global_load_lds(
                (const AS1 unsigned int*)(gA + (size_t)row * K_DIM + k0 + lcol),
                (AS3 unsigned int*)&ldsA[chunk * 512], 16, 0, 0);
        }
#pragma unroll
        for (int r = 0; r < 4; ++r) {
            const int chunk = r * 4 + w;
            const int row = chunk * 8 + lrow;
            __builtin_amdgcn_global_load_lds(
                (const AS1 unsigned int*)(gB + (size_t)row * K_DIM + k0 + lcol),
                (AS3 unsigned int*)&ldsB[chunk * 512], 16, 0, 0);
        }
        __syncthreads();
#pragma unroll
        for (int kk = 0; kk < 64; kk += 32) {
            bf16x8 af[4], bfr[4];
            const int krd = kk + (lane >> 4) * 8;
            const int rsel = lane & 15;
#pragma unroll
            for (int mi = 0; mi < 4; ++mi)
                af[mi] = *(const bf16x8*)&ldsA[(wr * 64 + mi * 16 + rsel) * 64 + krd];
#pragma unroll
            for (int ni = 0; ni < 4; ++ni)
                bfr[ni] = *(const bf16x8*)&ldsB[(wc * 64 + ni * 16 + rsel) * 64 + krd];
#pragma unroll
            for (int mi = 0; mi < 4; ++mi)
#pragma unroll
                for (int ni = 0; ni < 4; ++ni)
                    acc[mi][ni] = __builtin_amdgcn_mfma_f32_16x16x32_bf16(
                        af[mi], bfr[ni], acc[mi][ni], 0, 0, 0);
        }
    }
    const int row0 = by * 128 + wr * 64;
    const int col0 = bx * 128 + wc * 64;
    float ia[4];
#pragma unroll
    for (int ni = 0; ni < 4; ++ni) ia[ni] = inva[col0 + ni * 16 + (lane & 15)];
    float ic[4][4];
#pragma unroll
    for (int mi = 0; mi < 4; ++mi)
#pragma unroll
        for (int r = 0; r < 4; ++r)
            ic[mi][r] = invc[row0 + mi * 16 + (lane >> 4) * 4 + r];
    float local = 0.f;
#pragma unroll
    for (int mi = 0; mi < 4; ++mi) {
#pragma unroll
        for (int ni = 0; ni < 4; ++ni) {
            const int col = col0 + ni * 16 + (lane & 15);
            const int rbase = row0 + mi * 16 + (lane >> 4) * 4;
#pragma unroll
            for (int r = 0; r < 4; ++r) {
                const float sim = acc[mi][ni][r] * ic[mi][r] * ia[ni];
                const float d2 = fmaxf(2.f - 2.f * sim, 0.f);
                if (rbase + r == col) {
                    local += d2;
                } else {
                    float t = fmaxf(MARGIN - sqrtf(d2), 0.f);
                    local += t * t;
                }
            }
        }
    }
#pragma unroll
    for (int off = 32; off; off >>= 1) local += __shfl_down(local, off);
    __shared__ float red[4];
    if (lane == 0) red[w] = local;
    __syncthreads();
    if (tid == 0) atomicAdd(acc_out, red[0] + red[1] + red[2] + red[3]);
}

__global__ void finalize(const float* __restrict__ acc, float* __restrict__ out) {
    if (threadIdx.x == 0 && blockIdx.x == 0)
        out[0] = acc[0] / (2.0f * N_ROWS);
}

extern "C" void kernel_launch(void* const* d_in, const int* in_sizes, int n_in,
                              void* d_out, int out_size, void* d_ws, size_t ws_size,
                              hipStream_t stream) {
    const float* c_in = (const float*)d_in[0];
    const float* a_in = (const float*)d_in[1];
    float* out = (float*)d_out;

    char* ws = (char*)d_ws;
    float* accp = (float*)ws;
    unsigned int* counter = (unsigned int*)(ws + 4);
    float* invc = (float*)(ws + 64);
    float* inva = (float*)(ws + 64 + 2048 * 4);
    unsigned short* Cbf = (unsigned short*)(ws + 32768);
    unsigned short* Abf = Cbf + (size_t)N_ROWS * K_DIM;
    unsigned short* simPart = (unsigned short*)(ws + 32768 + 2 * (size_t)N_ROWS * K_DIM * 2);

    const size_t baseNeed = 32768 + 2 * (size_t)N_ROWS * K_DIM * 2;      // 67.1 MB
    const size_t partBytes = (size_t)N_ROWS * N_ROWS * 2;                 // 8.39 MB

    int nsplit = 0;
    if (ws_size >= baseNeed + 4 * partBytes) nsplit = 4;
    else if (ws_size >= baseNeed + 2 * partBytes) nsplit = 2;
    else if (ws_size >= baseNeed + 1 * partBytes) nsplit = 1;

    norm_convert<<<dim3(N_ROWS, 2), 256, 0, stream>>>(c_in, a_in, Cbf, Abf,
                                                      invc, inva, accp, counter);
    if (nsplit > 0) {
        gemm_partial8<<<dim3(64, nsplit), 512, 0, stream>>>(Cbf, Abf, simPart,
                                                            K_DIM / nsplit);
        epilogue_loss<<<dim3(N_ROWS), 256, 0, stream>>>(simPart, nsplit, invc, inva,
                                                        accp, counter, out);
    } else {
        gemm_loss<<<dim3(256), 256, 0, stream>>>(Cbf, Abf, invc, inva, accp);
        finalize<<<1, 64, 0, stream>>>(accp, out);
    }
}

// Round 7
// 268.559 us; speedup vs baseline: 1.1518x; 1.0768x over previous
//
#include <hip/hip_runtime.h>
#include <hip/hip_bf16.h>

#define N_ROWS 2048
#define K_DIM  8192
#define MARGIN 0.2f

typedef __attribute__((ext_vector_type(4))) float f32x4;
typedef __bf16 bf16x8 __attribute__((ext_vector_type(8)));

#define AS1 __attribute__((address_space(1)))
#define AS3 __attribute__((address_space(3)))

// ---------------- workspace layout (split path) ----------------
// [0]        : float acc
// [4]        : unsigned counter
// [64]       : inv_c (2048 f32)
// [64+8192]  : inv_a (2048 f32)
// [32768]    : Cbf (2048*8192 u16)  33.55 MB
// [+33.55MB] : Abf (2048*8192 u16)  33.55 MB
// [67141632] : simPart bf16, nsplit * 2048*2048*2 B (8.39 MB each)

__device__ inline unsigned short f2bf_rne(float f) {
    unsigned int u = __float_as_uint(f);
    unsigned int r = (u + 0x7fffu + ((u >> 16) & 1u)) >> 16;
    return (unsigned short)r;
}
__device__ inline float bf2f(unsigned short u) {
    return __uint_as_float(((unsigned int)u) << 16);
}

// One block per (row, matrix): 1/max(||row||,eps) + bf16 copy of raw row.
__global__ __launch_bounds__(256) void norm_convert(
    const float* __restrict__ c_in, const float* __restrict__ a_in,
    unsigned short* __restrict__ Cbf, unsigned short* __restrict__ Abf,
    float* __restrict__ invc, float* __restrict__ inva,
    float* __restrict__ acc, unsigned int* __restrict__ counter) {
    const int row = blockIdx.x;
    const int which = blockIdx.y;
    if (row == 0 && which == 0 && threadIdx.x == 0) { acc[0] = 0.f; counter[0] = 0u; }
    const float* src = (which == 0 ? c_in : a_in) + (size_t)row * K_DIM;
    unsigned short* dst = (which == 0 ? Cbf : Abf) + (size_t)row * K_DIM;
    float* invp = (which == 0 ? invc : inva);

    const float4* src4 = (const float4*)src;
    float s = 0.f;
#pragma unroll
    for (int i = 0; i < 8; ++i) {
        float4 v = src4[threadIdx.x + i * 256];
        s += v.x * v.x + v.y * v.y + v.z * v.z + v.w * v.w;
        ushort4 o;
        o.x = f2bf_rne(v.x);
        o.y = f2bf_rne(v.y);
        o.z = f2bf_rne(v.z);
        o.w = f2bf_rne(v.w);
        ((ushort4*)dst)[threadIdx.x + i * 256] = o;
    }
#pragma unroll
    for (int off = 32; off; off >>= 1) s += __shfl_down(s, off);
    __shared__ float red[4];
    if ((threadIdx.x & 63) == 0) red[threadIdx.x >> 6] = s;
    __syncthreads();
    if (threadIdx.x == 0) {
        float t = red[0] + red[1] + red[2] + red[3];
        invp[row] = 1.0f / fmaxf(sqrtf(t), 1e-12f);
    }
}

// ---------------- 8-phase 256x256 split-K GEMM (T2-swizzled LDS) ----------
// 512 threads = 8 waves (2M x 4N). Per-wave output 128x64.
// LDS: 8 slots x 16KB. T2 swizzle: elem col' = col ^ ((row&7)<<3), applied
// to the GLOBAL staging source (LDS dest stays linear, rule #21) and to the
// ds_read column. Counted vmcnt only at phases 4/8.

#define BAR __builtin_amdgcn_s_barrier()
#define VMCNT4 asm volatile("s_waitcnt vmcnt(4)" ::: "memory")
#define VMCNT8 asm volatile("s_waitcnt vmcnt(8)" ::: "memory")

// stage one 128x64 half-tile (16KB) into LDS slot: 2 x global_load_lds dwordx4
// global source column is pre-swizzled (scolsw); LDS dest is linear.
#define STAGE(gbase, halfrowbase, kt, slot) do {                                   \
    const unsigned short* _s = (gbase) + (size_t)((halfrowbase) + srow) * K_DIM    \
                               + (size_t)(K0 + (kt) * 64 + scolsw);                \
    __builtin_amdgcn_global_load_lds((const AS1 unsigned int*)_s,                  \
        (AS3 unsigned int*)&lds[(slot) * 8192 + tid * 8], 16, 0, 0);               \
    __builtin_amdgcn_global_load_lds((const AS1 unsigned int*)(_s + (size_t)64 * K_DIM), \
        (AS3 unsigned int*)&lds[(slot) * 8192 + 4096 + tid * 8], 16, 0, 0);        \
} while (0)

// read 4 A-fragment rows (mi = mh*4 .. +4), both k-slices (swizzled cols)
#define READ_A(p, mh) do {                                                         \
    const int _sb = ((p) * 4 + wm) * 8192;                                         \
    _Pragma("unroll") for (int r = 0; r < 4; ++r) {                                \
        const int _row = (mh) * 64 + r * 16 + rsel;                                \
        a_r[r][0] = *(const bf16x8*)&lds[_sb + _row * 64 + csw0];                   \
        a_r[r][1] = *(const bf16x8*)&lds[_sb + _row * 64 + csw1];                   \
    } } while (0)

// read 2 B-fragment cols (ni = nh*2 .. +2), both k-slices (swizzled cols)
#define READ_B(p, nh) do {                                                         \
    const int _sb = ((p) * 4 + 2 + (wn >> 1)) * 8192;                              \
    _Pragma("unroll") for (int q = 0; q < 2; ++q) {                                \
        const int _ni = (nh) * 2 + q;                                              \
        const int _row = (wn & 1) * 64 + _ni * 16 + rsel;                          \
        b_r[_ni][0] = *(const bf16x8*)&lds[_sb + _row * 64 + csw0];                \
        b_r[_ni][1] = *(const bf16x8*)&lds[_sb + _row * 64 + csw1];                \
    } } while (0)

// 16 MFMA = one C-quadrant over K=64
#define MFMA_Q(mh, nh) do {                                                        \
    __builtin_amdgcn_s_setprio(1);                                                 \
    _Pragma("unroll") for (int r = 0; r < 4; ++r)                                  \
    _Pragma("unroll") for (int q = 0; q < 2; ++q) {                                \
        const int _mi = (mh) * 4 + r, _ni = (nh) * 2 + q;                          \
        acc[_mi][_ni] = __builtin_amdgcn_mfma_f32_16x16x32_bf16(                   \
            a_r[r][0], b_r[_ni][0], acc[_mi][_ni], 0, 0, 0);                       \
        acc[_mi][_ni] = __builtin_amdgcn_mfma_f32_16x16x32_bf16(                   \
            a_r[r][1], b_r[_ni][1], acc[_mi][_ni], 0, 0, 0);                       \
    }                                                                              \
    __builtin_amdgcn_s_setprio(0);                                                 \
} while (0)

__global__ __launch_bounds__(512, 2) void gemm_partial8(
    const unsigned short* __restrict__ Cbf, const unsigned short* __restrict__ Abf,
    unsigned short* __restrict__ simPart, int kchunk) {
    __shared__ unsigned short lds[65536];   // 8 slots x 8192 elems = 128 KB

    const int b = blockIdx.x;               // 0..63
    const int swz = (b & 7) * 8 + (b >> 3); // XCD-contiguous
    const int bm = swz >> 3, bn = swz & 7;
    const int kc = blockIdx.y;
    const int K0 = kc * kchunk;
    const int NT = kchunk >> 6;             // K-tiles (even)

    const int tid = threadIdx.x;
    const int lane = tid & 63;
    const int w = tid >> 6;
    const int wm = w >> 2, wn = w & 3;
    const int rsel = lane & 15;
    const int khi = (lane >> 4) * 8;
    const int srow = tid >> 3;              // staging row 0..63
    // T2 swizzle constants:
    const int scolsw = (((tid & 7) ^ ((tid >> 3) & 7)) * 8);   // staging global col
    const int csw0 = khi ^ ((rsel & 7) << 3);                  // read col, k-slice 0
    const int csw1 = (32 + khi) ^ ((rsel & 7) << 3);           // read col, k-slice 1

    const unsigned short* gA = Cbf + (size_t)(bm * 256) * K_DIM;
    const unsigned short* gB = Abf + (size_t)(bn * 256) * K_DIM;

    f32x4 acc[8][4];
#pragma unroll
    for (int i = 0; i < 8; ++i)
#pragma unroll
        for (int j = 0; j < 4; ++j) acc[i][j] = (f32x4)0.f;

    bf16x8 a_r[4][2], b_r[4][2];

    // prologue: K-tile 0 -> slots 0-3, K-tile 1 -> slots 4-7
    STAGE(gA, 0, 0, 0); STAGE(gA, 128, 0, 1); STAGE(gB, 0, 0, 2); STAGE(gB, 128, 0, 3);
    STAGE(gA, 0, 1, 4); STAGE(gA, 128, 1, 5); STAGE(gB, 0, 1, 6); STAGE(gB, 128, 1, 7);
    VMCNT8;   // slots 0-3 landed; 4-7 still in flight
    BAR;

    for (int it = 0; it < NT / 2; ++it) {
        const int t1 = 2 * it + 1;
        const int e2 = (2 * it + 2 < NT) ? 2 * it + 2 : NT - 1;  // clamped: staged, never read
        const int e3 = (2 * it + 3 < NT) ? 2 * it + 3 : NT - 1;
        // ---- K-tile 2it (slots 0-3) ----
        // ph1
        READ_A(0, 0); READ_B(0, 0);
        STAGE(gA, 0, t1, 4);
        BAR; MFMA_Q(0, 0); BAR;
        // ph2
        READ_B(0, 1);
        STAGE(gA, 128, t1, 5);
        BAR; MFMA_Q(0, 1); BAR;
        // ph3
        READ_A(0, 1);
        STAGE(gB, 0, e2, 2);
        BAR; MFMA_Q(1, 1); BAR;
        // ph4
        STAGE(gB, 128, e2, 3);
        VMCNT4;           // slots 4-7 guaranteed resident for phases 5-8
        BAR; MFMA_Q(1, 0); BAR;
        // ---- K-tile 2it+1 (slots 4-7) ----
        // ph5
        READ_A(1, 0); READ_B(1, 0);
        STAGE(gA, 0, e2, 0);
        BAR; MFMA_Q(0, 0); BAR;
        // ph6
        READ_B(1, 1);
        STAGE(gA, 128, e2, 1);
        BAR; MFMA_Q(0, 1); BAR;
        // ph7
        READ_A(1, 1);
        STAGE(gB, 0, e3, 6);
        BAR; MFMA_Q(1, 1); BAR;
        // ph8
        STAGE(gB, 128, e3, 7);
        VMCNT4;           // slots 0-3 guaranteed resident for next iter
        BAR; MFMA_Q(1, 0); BAR;
    }

    // write bf16 partial tile
    unsigned short* outp = simPart + ((size_t)kc << 22);
    const int row0 = bm * 256 + wm * 128;
    const int col0 = bn * 256 + wn * 64;
#pragma unroll
    for (int mi = 0; mi < 8; ++mi) {
#pragma unroll
        for (int ni = 0; ni < 4; ++ni) {
            const int gc = col0 + ni * 16 + (lane & 15);
            const int gr0 = row0 + mi * 16 + (lane >> 4) * 4;
#pragma unroll
            for (int r = 0; r < 4; ++r)
                outp[(size_t)(gr0 + r) * N_ROWS + gc] = f2bf_rne(acc[mi][ni][r]);
        }
    }
}

// One block per row: sum partials, scale by inv-norms, hinge/diag, reduce.
__global__ __launch_bounds__(256) void epilogue_loss(
    const unsigned short* __restrict__ simPart, int nsplit,
    const float* __restrict__ invc, const float* __restrict__ inva,
    float* __restrict__ acc, unsigned int* __restrict__ counter,
    float* __restrict__ out) {
    const int row = blockIdx.x;
    const int j0 = threadIdx.x * 8;
    float s[8];
#pragma unroll
    for (int e = 0; e < 8; ++e) s[e] = 0.f;
    for (int p = 0; p < nsplit; ++p) {
        const unsigned short* base = simPart + (((size_t)p) << 22) + (size_t)row * N_ROWS + j0;
        ushort4 u0 = ((const ushort4*)base)[0];
        ushort4 u1 = ((const ushort4*)base)[1];
        s[0] += bf2f(u0.x); s[1] += bf2f(u0.y); s[2] += bf2f(u0.z); s[3] += bf2f(u0.w);
        s[4] += bf2f(u1.x); s[5] += bf2f(u1.y); s[6] += bf2f(u1.z); s[7] += bf2f(u1.w);
    }
    const float ic = invc[row];
    float local = 0.f;
#pragma unroll
    for (int e = 0; e < 8; ++e) {
        const int j = j0 + e;
        const float sim = s[e] * ic * inva[j];
        const float d2 = fmaxf(2.f - 2.f * sim, 0.f);
        if (j == row) {
            local += d2;
        } else {
            float t = fmaxf(MARGIN - sqrtf(d2), 0.f);
            local += t * t;
        }
    }
#pragma unroll
    for (int off = 32; off; off >>= 1) local += __shfl_down(local, off);
    __shared__ float red[4];
    if ((threadIdx.x & 63) == 0) red[threadIdx.x >> 6] = local;
    __syncthreads();
    if (threadIdx.x == 0) {
        atomicAdd(acc, red[0] + red[1] + red[2] + red[3]);
        __threadfence();
        unsigned int old = atomicAdd(counter, 1u);
        if (old == gridDim.x - 1) {
            float total = atomicAdd(acc, 0.0f);
            out[0] = total / (2.0f * N_ROWS);
        }
    }
}

// ---------- fallback (round-1 verified): fused epilogue, grid 256 ----------
__global__ __launch_bounds__(256) void gemm_loss(
    const unsigned short* __restrict__ Cbf, const unsigned short* __restrict__ Abf,
    const float* __restrict__ invc, const float* __restrict__ inva,
    float* __restrict__ acc_out) {
    __shared__ unsigned short ldsA[128 * 64];
    __shared__ unsigned short ldsB[128 * 64];
    const int b = blockIdx.x;
    const int swz = (b & 7) * 32 + (b >> 3);
    const int bx = swz & 15;
    const int by = swz >> 4;
    const int tid  = threadIdx.x;
    const int lane = tid & 63;
    const int w    = tid >> 6;
    const int wr   = w >> 1;
    const int wc   = w & 1;
    f32x4 acc[4][4];
#pragma unroll
    for (int i = 0; i < 4; ++i)
#pragma unroll
        for (int j = 0; j < 4; ++j) acc[i][j] = (f32x4)0.f;
    const int lrow = lane >> 3;
    const int lcol = (lane & 7) * 8;
    const unsigned short* gA = Cbf + (size_t)(by * 128) * K_DIM;
    const unsigned short* gB = Abf + (size_t)(bx * 128) * K_DIM;
    for (int k0 = 0; k0 < K_DIM; k0 += 64) {
        __syncthreads();
#pragma unroll
        for (int r = 0; r < 4; ++r) {
            const int chunk = r * 4 + w;
            const int row = chunk * 8 + lrow;
            __builtin_amdgcn_global_load_lds(
                (const AS1 unsigned int*)(gA + (size_t)row * K_DIM + k0 + lcol),
                (AS3 unsigned int*)&ldsA[chunk * 512], 16, 0, 0);
        }
#pragma unroll
        for (int r = 0; r < 4; ++r) {
            const int chunk = r * 4 + w;
            const int row = chunk * 8 + lrow;
            __builtin_amdgcn_global_load_lds(
                (const AS1 unsigned int*)(gB + (size_t)row * K_DIM + k0 + lcol),
                (AS3 unsigned int*)&ldsB[chunk * 512], 16, 0, 0);
        }
        __syncthreads();
#pragma unroll
        for (int kk = 0; kk < 64; kk += 32) {
            bf16x8 af[4], bfr[4];
            const int krd = kk + (lane >> 4) * 8;
            const int rsel = lane & 15;
#pragma unroll
            for (int mi = 0; mi < 4; ++mi)
                af[mi] = *(const bf16x8*)&ldsA[(wr * 64 + mi * 16 + rsel) * 64 + krd];
#pragma unroll
            for (int ni = 0; ni < 4; ++ni)
                bfr[ni] = *(const bf16x8*)&ldsB[(wc * 64 + ni * 16 + rsel) * 64 + krd];
#pragma unroll
            for (int mi = 0; mi < 4; ++mi)
#pragma unroll
                for (int ni = 0; ni < 4; ++ni)
                    acc[mi][ni] = __builtin_amdgcn_mfma_f32_16x16x32_bf16(
                        af[mi], bfr[ni], acc[mi][ni], 0, 0, 0);
        }
    }
    const int row0 = by * 128 + wr * 64;
    const int col0 = bx * 128 + wc * 64;
    float ia[4];
#pragma unroll
    for (int ni = 0; ni < 4; ++ni) ia[ni] = inva[col0 + ni * 16 + (lane & 15)];
    float ic[4][4];
#pragma unroll
    for (int mi = 0; mi < 4; ++mi)
#pragma unroll
        for (int r = 0; r < 4; ++r)
            ic[mi][r] = invc[row0 + mi * 16 + (lane >> 4) * 4 + r];
    float local = 0.f;
#pragma unroll
    for (int mi = 0; mi < 4; ++mi) {
#pragma unroll
        for (int ni = 0; ni < 4; ++ni) {
            const int col = col0 + ni * 16 + (lane & 15);
            const int rbase = row0 + mi * 16 + (lane >> 4) * 4;
#pragma unroll
            for (int r = 0; r < 4; ++r) {
                const float sim = acc[mi][ni][r] * ic[mi][r] * ia[ni];
                const float d2 = fmaxf(2.f - 2.f * sim, 0.f);
                if (rbase + r == col) {
                    local += d2;
                } else {
                    float t = fmaxf(MARGIN - sqrtf(d2), 0.f);
                    local += t * t;
                }
            }
        }
    }
#pragma unroll
    for (int off = 32; off; off >>= 1) local += __shfl_down(local, off);
    __shared__ float red[4];
    if (lane == 0) red[w] = local;
    __syncthreads();
    if (tid == 0) atomicAdd(acc_out, red[0] + red[1] + red[2] + red[3]);
}

__global__ void finalize(const float* __restrict__ acc, float* __restrict__ out) {
    if (threadIdx.x == 0 && blockIdx.x == 0)
        out[0] = acc[0] / (2.0f * N_ROWS);
}

extern "C" void kernel_launch(void* const* d_in, const int* in_sizes, int n_in,
                              void* d_out, int out_size, void* d_ws, size_t ws_size,
                              hipStream_t stream) {
    const float* c_in = (const float*)d_in[0];
    const float* a_in = (const float*)d_in[1];
    float* out = (float*)d_out;

    char* ws = (char*)d_ws;
    float* accp = (float*)ws;
    unsigned int* counter = (unsigned int*)(ws + 4);
    float* invc = (float*)(ws + 64);
    float* inva = (float*)(ws + 64 + 2048 * 4);
    unsigned short* Cbf = (unsigned short*)(ws + 32768);
    unsigned short* Abf = Cbf + (size_t)N_ROWS * K_DIM;
    unsigned short* simPart = (unsigned short*)(ws + 32768 + 2 * (size_t)N_ROWS * K_DIM * 2);

    const size_t baseNeed = 32768 + 2 * (size_t)N_ROWS * K_DIM * 2;      // 67.1 MB
    const size_t partBytes = (size_t)N_ROWS * N_ROWS * 2;                 // 8.39 MB

    int nsplit = 0;
    if (ws_size >= baseNeed + 4 * partBytes) nsplit = 4;
    else if (ws_size >= baseNeed + 2 * partBytes) nsplit = 2;
    else if (ws_size >= baseNeed + 1 * partBytes) nsplit = 1;

    norm_convert<<<dim3(N_ROWS, 2), 256, 0, stream>>>(c_in, a_in, Cbf, Abf,
                                                      invc, inva, accp, counter);
    if (nsplit > 0) {
        gemm_partial8<<<dim3(64, nsplit), 512, 0, stream>>>(Cbf, Abf, simPart,
                                                            K_DIM / nsplit);
        epilogue_loss<<<dim3(N_ROWS), 256, 0, stream>>>(simPart, nsplit, invc, inva,
                                                        accp, counter, out);
    } else {
        gemm_loss<<<dim3(256), 256, 0, stream>>>(Cbf, Abf, invc, inva, accp);
        finalize<<<1, 64, 0, stream>>>(accp, out);
    }
}

// Round 14
// 234.376 us; speedup vs baseline: 1.3198x; 1.1459x over previous
//
#include <hip/hip_runtime.h>
#include <hip/hip_bf16.h>

#define N_ROWS 2048
#define K_DIM  8192
#define MARGIN 0.2f

typedef __attribute__((ext_vector_type(4))) float f32x4;
typedef __bf16 bf16x8 __attribute__((ext_vector_type(8)));

#define AS1 __attribute__((address_space(1)))
#define AS3 __attribute__((address_space(3)))

// ---------------- workspace layout (split path) ----------------
// [0]        : float acc
// [4]        : unsigned counter
// [64]       : inv_c (2048 f32)
// [64+8192]  : inv_a (2048 f32)
// [32768]    : Cbf (2048*8192 u16)  33.55 MB
// [+33.55MB] : Abf (2048*8192 u16)  33.55 MB
// [67141632] : simPart bf16, nsplit * 2048*2048*2 B (8.39 MB each)

__device__ inline unsigned short f2bf_rne(float f) {
    unsigned int u = __float_as_uint(f);
    unsigned int r = (u + 0x7fffu + ((u >> 16) & 1u)) >> 16;
    return (unsigned short)r;
}
__device__ inline float bf2f(unsigned short u) {
    return __uint_as_float(((unsigned int)u) << 16);
}

// One block per (row, matrix): 1/max(||row||,eps) + bf16 copy of raw row.
__global__ __launch_bounds__(256) void norm_convert(
    const float* __restrict__ c_in, const float* __restrict__ a_in,
    unsigned short* __restrict__ Cbf, unsigned short* __restrict__ Abf,
    float* __restrict__ invc, float* __restrict__ inva,
    float* __restrict__ acc, unsigned int* __restrict__ counter) {
    const int row = blockIdx.x;
    const int which = blockIdx.y;
    if (row == 0 && which == 0 && threadIdx.x == 0) { acc[0] = 0.f; counter[0] = 0u; }
    const float* src = (which == 0 ? c_in : a_in) + (size_t)row * K_DIM;
    unsigned short* dst = (which == 0 ? Cbf : Abf) + (size_t)row * K_DIM;
    float* invp = (which == 0 ? invc : inva);

    const float4* src4 = (const float4*)src;
    float s = 0.f;
#pragma unroll
    for (int i = 0; i < 8; ++i) {
        float4 v = src4[threadIdx.x + i * 256];
        s += v.x * v.x + v.y * v.y + v.z * v.z + v.w * v.w;
        ushort4 o;
        o.x = f2bf_rne(v.x);
        o.y = f2bf_rne(v.y);
        o.z = f2bf_rne(v.z);
        o.w = f2bf_rne(v.w);
        ((ushort4*)dst)[threadIdx.x + i * 256] = o;
    }
#pragma unroll
    for (int off = 32; off; off >>= 1) s += __shfl_down(s, off);
    __shared__ float red[4];
    if ((threadIdx.x & 63) == 0) red[threadIdx.x >> 6] = s;
    __syncthreads();
    if (threadIdx.x == 0) {
        float t = red[0] + red[1] + red[2] + red[3];
        invp[row] = 1.0f / fmaxf(sqrtf(t), 1e-12f);
    }
}

// ---------------- 8-phase 256x256 split-K GEMM (T2-swizzled LDS) ----------
// 512 threads = 8 waves (2M x 4N). Per-wave output 128x64.
// LDS: 8 slots x 16KB. T2 swizzle: elem col' = col ^ ((row&7)<<3), applied
// to the GLOBAL staging source (LDS dest stays linear, rule #21) and to the
// ds_read column. Counted vmcnt only at phases 4/8.

#define BAR __builtin_amdgcn_s_barrier()
#define VMCNT4 asm volatile("s_waitcnt vmcnt(4)" ::: "memory")
#define VMCNT8 asm volatile("s_waitcnt vmcnt(8)" ::: "memory")

// stage one 128x64 half-tile (16KB) into LDS slot: 2 x global_load_lds dwordx4
// global source column is pre-swizzled (scolsw); LDS dest is linear.
#define STAGE(gbase, halfrowbase, kt, slot) do {                                   \
    const unsigned short* _s = (gbase) + (size_t)((halfrowbase) + srow) * K_DIM    \
                               + (size_t)(K0 + (kt) * 64 + scolsw);                \
    __builtin_amdgcn_global_load_lds((const AS1 unsigned int*)_s,                  \
        (AS3 unsigned int*)&lds[(slot) * 8192 + tid * 8], 16, 0, 0);               \
    __builtin_amdgcn_global_load_lds((const AS1 unsigned int*)(_s + (size_t)64 * K_DIM), \
        (AS3 unsigned int*)&lds[(slot) * 8192 + 4096 + tid * 8], 16, 0, 0);        \
} while (0)

// read 4 A-fragment rows (mi = mh*4 .. +4), both k-slices (swizzled cols)
#define READ_A(p, mh) do {                                                         \
    const int _sb = ((p) * 4 + wm) * 8192;                                         \
    _Pragma("unroll") for (int r = 0; r < 4; ++r) {                                \
        const int _row = (mh) * 64 + r * 16 + rsel;                                \
        a_r[r][0] = *(const bf16x8*)&lds[_sb + _row * 64 + csw0];                   \
        a_r[r][1] = *(const bf16x8*)&lds[_sb + _row * 64 + csw1];                   \
    } } while (0)

// read 2 B-fragment cols (ni = nh*2 .. +2), both k-slices (swizzled cols)
#define READ_B(p, nh) do {                                                         \
    const int _sb = ((p) * 4 + 2 + (wn >> 1)) * 8192;                              \
    _Pragma("unroll") for (int q = 0; q < 2; ++q) {                                \
        const int _ni = (nh) * 2 + q;                                              \
        const int _row = (wn & 1) * 64 + _ni * 16 + rsel;                          \
        b_r[_ni][0] = *(const bf16x8*)&lds[_sb + _row * 64 + csw0];                \
        b_r[_ni][1] = *(const bf16x8*)&lds[_sb + _row * 64 + csw1];                \
    } } while (0)

// 16 MFMA = one C-quadrant over K=64
#define MFMA_Q(mh, nh) do {                                                        \
    __builtin_amdgcn_s_setprio(1);                                                 \
    _Pragma("unroll") for (int r = 0; r < 4; ++r)                                  \
    _Pragma("unroll") for (int q = 0; q < 2; ++q) {                                \
        const int _mi = (mh) * 4 + r, _ni = (nh) * 2 + q;                          \
        acc[_mi][_ni] = __builtin_amdgcn_mfma_f32_16x16x32_bf16(                   \
            a_r[r][0], b_r[_ni][0], acc[_mi][_ni], 0, 0, 0);                       \
        acc[_mi][_ni] = __builtin_amdgcn_mfma_f32_16x16x32_bf16(                   \
            a_r[r][1], b_r[_ni][1], acc[_mi][_ni], 0, 0, 0);                       \
    }                                                                              \
    __builtin_amdgcn_s_setprio(0);                                                 \
} while (0)

__global__ __launch_bounds__(512, 2) void gemm_partial8(
    const unsigned short* __restrict__ Cbf, const unsigned short* __restrict__ Abf,
    unsigned short* __restrict__ simPart, int kchunk) {
    __shared__ unsigned short lds[65536];   // 8 slots x 8192 elems = 128 KB

    const int b = blockIdx.x;               // 0..63
    const int swz = (b & 7) * 8 + (b >> 3); // XCD-contiguous
    const int bm = swz >> 3, bn = swz & 7;
    const int kc = blockIdx.y;
    const int K0 = kc * kchunk;
    const int NT = kchunk >> 6;             // K-tiles (even)

    const int tid = threadIdx.x;
    const int lane = tid & 63;
    const int w = tid >> 6;
    const int wm = w >> 2, wn = w & 3;
    const int rsel = lane & 15;
    const int khi = (lane >> 4) * 8;
    const int srow = tid >> 3;              // staging row 0..63
    // T2 swizzle constants:
    const int scolsw = (((tid & 7) ^ ((tid >> 3) & 7)) * 8);   // staging global col
    const int csw0 = khi ^ ((rsel & 7) << 3);                  // read col, k-slice 0
    const int csw1 = (32 + khi) ^ ((rsel & 7) << 3);           // read col, k-slice 1

    const unsigned short* gA = Cbf + (size_t)(bm * 256) * K_DIM;
    const unsigned short* gB = Abf + (size_t)(bn * 256) * K_DIM;

    f32x4 acc[8][4];
#pragma unroll
    for (int i = 0; i < 8; ++i)
#pragma unroll
        for (int j = 0; j < 4; ++j) acc[i][j] = (f32x4)0.f;

    bf16x8 a_r[4][2], b_r[4][2];

    // prologue: K-tile 0 -> slots 0-3, K-tile 1 -> slots 4-7
    STAGE(gA, 0, 0, 0); STAGE(gA, 128, 0, 1); STAGE(gB, 0, 0, 2); STAGE(gB, 128, 0, 3);
    STAGE(gA, 0, 1, 4); STAGE(gA, 128, 1, 5); STAGE(gB, 0, 1, 6); STAGE(gB, 128, 1, 7);
    VMCNT8;   // slots 0-3 landed; 4-7 still in flight
    BAR;

    for (int it = 0; it < NT / 2; ++it) {
        const int t1 = 2 * it + 1;
        const int e2 = (2 * it + 2 < NT) ? 2 * it + 2 : NT - 1;  // clamped: staged, never read
        const int e3 = (2 * it + 3 < NT) ? 2 * it + 3 : NT - 1;
        // ---- K-tile 2it (slots 0-3) ----
        // ph1
        READ_A(0, 0); READ_B(0, 0);
        STAGE(gA, 0, t1, 4);
        BAR; MFMA_Q(0, 0); BAR;
        // ph2
        READ_B(0, 1);
        STAGE(gA, 128, t1, 5);
        BAR; MFMA_Q(0, 1); BAR;
        // ph3
        READ_A(0, 1);
        STAGE(gB, 0, e2, 2);
        BAR; MFMA_Q(1, 1); BAR;
        // ph4
        STAGE(gB, 128, e2, 3);
        VMCNT4;           // slots 4-7 guaranteed resident for phases 5-8
        BAR; MFMA_Q(1, 0); BAR;
        // ---- K-tile 2it+1 (slots 4-7) ----
        // ph5
        READ_A(1, 0); READ_B(1, 0);
        STAGE(gA, 0, e2, 0);
        BAR; MFMA_Q(0, 0); BAR;
        // ph6
        READ_B(1, 1);
        STAGE(gA, 128, e2, 1);
        BAR; MFMA_Q(0, 1); BAR;
        // ph7
        READ_A(1, 1);
        STAGE(gB, 0, e3, 6);
        BAR; MFMA_Q(1, 1); BAR;
        // ph8
        STAGE(gB, 128, e3, 7);
        VMCNT4;           // slots 0-3 guaranteed resident for next iter
        BAR; MFMA_Q(1, 0); BAR;
    }

    // write bf16 partial tile
    unsigned short* outp = simPart + ((size_t)kc << 22);
    const int row0 = bm * 256 + wm * 128;
    const int col0 = bn * 256 + wn * 64;
#pragma unroll
    for (int mi = 0; mi < 8; ++mi) {
#pragma unroll
        for (int ni = 0; ni < 4; ++ni) {
            const int gc = col0 + ni * 16 + (lane & 15);
            const int gr0 = row0 + mi * 16 + (lane >> 4) * 4;
#pragma unroll
            for (int r = 0; r < 4; ++r)
                outp[(size_t)(gr0 + r) * N_ROWS + gc] = f2bf_rne(acc[mi][ni][r]);
        }
    }
}

// 256 blocks x 8 rows each: sum partials, scale by inv-norms, hinge/diag,
// block-reduce. 8x fewer blocks -> 256 (not 2048) serialized atomics on the
// shared acc/counter cachelines. Last block (ticket) writes the final scalar.
#define EPI_ROWS 8
__global__ __launch_bounds__(256) void epilogue_loss(
    const unsigned short* __restrict__ simPart, int nsplit,
    const float* __restrict__ invc, const float* __restrict__ inva,
    float* __restrict__ acc, unsigned int* __restrict__ counter,
    float* __restrict__ out) {
    const int j0 = threadIdx.x * 8;
    float ia[8];
#pragma unroll
    for (int e = 0; e < 8; ++e) ia[e] = inva[j0 + e];

    float local = 0.f;
    for (int rr = 0; rr < EPI_ROWS; ++rr) {
        const int row = blockIdx.x * EPI_ROWS + rr;
        float s[8];
#pragma unroll
        for (int e = 0; e < 8; ++e) s[e] = 0.f;
        for (int p = 0; p < nsplit; ++p) {
            const unsigned short* base = simPart + (((size_t)p) << 22) + (size_t)row * N_ROWS + j0;
            ushort4 u0 = ((const ushort4*)base)[0];
            ushort4 u1 = ((const ushort4*)base)[1];
            s[0] += bf2f(u0.x); s[1] += bf2f(u0.y); s[2] += bf2f(u0.z); s[3] += bf2f(u0.w);
            s[4] += bf2f(u1.x); s[5] += bf2f(u1.y); s[6] += bf2f(u1.z); s[7] += bf2f(u1.w);
        }
        const float ic = invc[row];
#pragma unroll
        for (int e = 0; e < 8; ++e) {
            const int j = j0 + e;
            const float sim = s[e] * ic * ia[e];
            const float d2 = fmaxf(2.f - 2.f * sim, 0.f);
            if (j == row) {
                local += d2;
            } else {
                float t = fmaxf(MARGIN - sqrtf(d2), 0.f);
                local += t * t;
            }
        }
    }
#pragma unroll
    for (int off = 32; off; off >>= 1) local += __shfl_down(local, off);
    __shared__ float red[4];
    if ((threadIdx.x & 63) == 0) red[threadIdx.x >> 6] = local;
    __syncthreads();
    if (threadIdx.x == 0) {
        atomicAdd(acc, red[0] + red[1] + red[2] + red[3]);
        __threadfence();
        unsigned int old = atomicAdd(counter, 1u);
        if (old == gridDim.x - 1) {
            float total = atomicAdd(acc, 0.0f);
            out[0] = total / (2.0f * N_ROWS);
        }
    }
}

// ---------- fallback (round-1 verified): fused epilogue, grid 256 ----------
__global__ __launch_bounds__(256) void gemm_loss(
    const unsigned short* __restrict__ Cbf, const unsigned short* __restrict__ Abf,
    const float* __restrict__ invc, const float* __restrict__ inva,
    float* __restrict__ acc_out) {
    __shared__ unsigned short ldsA[128 * 64];
    __shared__ unsigned short ldsB[128 * 64];
    const int b = blockIdx.x;
    const int swz = (b & 7) * 32 + (b >> 3);
    const int bx = swz & 15;
    const int by = swz >> 4;
    const int tid  = threadIdx.x;
    const int lane = tid & 63;
    const int w    = tid >> 6;
    const int wr   = w >> 1;
    const int wc   = w & 1;
    f32x4 acc[4][4];
#pragma unroll
    for (int i = 0; i < 4; ++i)
#pragma unroll
        for (int j = 0; j < 4; ++j) acc[i][j] = (f32x4)0.f;
    const int lrow = lane >> 3;
    const int lcol = (lane & 7) * 8;
    const unsigned short* gA = Cbf + (size_t)(by * 128) * K_DIM;
    const unsigned short* gB = Abf + (size_t)(bx * 128) * K_DIM;
    for (int k0 = 0; k0 < K_DIM; k0 += 64) {
        __syncthreads();
#pragma unroll
        for (int r = 0; r < 4; ++r) {
            const int chunk = r * 4 + w;
            const int row = chunk * 8 + lrow;
            __builtin_amdgcn_global_load_lds(
                (const AS1 unsigned int*)(gA + (size_t)row * K_DIM + k0 + lcol),
                (AS3 unsigned int*)&ldsA[chunk * 512], 16, 0, 0);
        }
#pragma unroll
        for (int r = 0; r < 4; ++r) {
            const int chunk = r * 4 + w;
            const int row = chunk * 8 + lrow;
            __builtin_amdgcn_global_load_lds(
                (const AS1 unsigned int*)(gB + (size_t)row * K_DIM + k0 + lcol),
                (AS3 unsigned int*)&ldsB[chunk * 512], 16, 0, 0);
        }
        __syncthreads();
#pragma unroll
        for (int kk = 0; kk < 64; kk += 32) {
            bf16x8 af[4], bfr[4];
            const int krd = kk + (lane >> 4) * 8;
            const int rsel = lane & 15;
#pragma unroll
            for (int mi = 0; mi < 4; ++mi)
                af[mi] = *(const bf16x8*)&ldsA[(wr * 64 + mi * 16 + rsel) * 64 + krd];
#pragma unroll
            for (int ni = 0; ni < 4; ++ni)
                bfr[ni] = *(const bf16x8*)&ldsB[(wc * 64 + ni * 16 + rsel) * 64 + krd];
#pragma unroll
            for (int mi = 0; mi < 4; ++mi)
#pragma unroll
                for (int ni = 0; ni < 4; ++ni)
                    acc[mi][ni] = __builtin_amdgcn_mfma_f32_16x16x32_bf16(
                        af[mi], bfr[ni], acc[mi][ni], 0, 0, 0);
        }
    }
    const int row0 = by * 128 + wr * 64;
    const int col0 = bx * 128 + wc * 64;
    float ia[4];
#pragma unroll
    for (int ni = 0; ni < 4; ++ni) ia[ni] = inva[col0 + ni * 16 + (lane & 15)];
    float ic[4][4];
#pragma unroll
    for (int mi = 0; mi < 4; ++mi)
#pragma unroll
        for (int r = 0; r < 4; ++r)
            ic[mi][r] = invc[row0 + mi * 16 + (lane >> 4) * 4 + r];
    float local = 0.f;
#pragma unroll
    for (int mi = 0; mi < 4; ++mi) {
#pragma unroll
        for (int ni = 0; ni < 4; ++ni) {
            const int col = col0 + ni * 16 + (lane & 15);
            const int rbase = row0 + mi * 16 + (lane >> 4) * 4;
#pragma unroll
            for (int r = 0; r < 4; ++r) {
                const float sim = acc[mi][ni][r] * ic[mi][r] * ia[ni];
                const float d2 = fmaxf(2.f - 2.f * sim, 0.f);
                if (rbase + r == col) {
                    local += d2;
                } else {
                    float t = fmaxf(MARGIN - sqrtf(d2), 0.f);
                    local += t * t;
                }
            }
        }
    }
#pragma unroll
    for (int off = 32; off; off >>= 1) local += __shfl_down(local, off);
    __shared__ float red[4];
    if (lane == 0) red[w] = local;
    __syncthreads();
    if (tid == 0) atomicAdd(acc_out, red[0] + red[1] + red[2] + red[3]);
}

__global__ void finalize(const float* __restrict__ acc, float* __restrict__ out) {
    if (threadIdx.x == 0 && blockIdx.x == 0)
        out[0] = acc[0] / (2.0f * N_ROWS);
}

extern "C" void kernel_launch(void* const* d_in, const int* in_sizes, int n_in,
                              void* d_out, int out_size, void* d_ws, size_t ws_size,
                              hipStream_t stream) {
    const float* c_in = (const float*)d_in[0];
    const float* a_in = (const float*)d_in[1];
    float* out = (float*)d_out;

    char* ws = (char*)d_ws;
    float* accp = (float*)ws;
    unsigned int* counter = (unsigned int*)(ws + 4);
    float* invc = (float*)(ws + 64);
    float* inva = (float*)(ws + 64 + 2048 * 4);
    unsigned short* Cbf = (unsigned short*)(ws + 32768);
    unsigned short* Abf = Cbf + (size_t)N_ROWS * K_DIM;
    unsigned short* simPart = (unsigned short*)(ws + 32768 + 2 * (size_t)N_ROWS * K_DIM * 2);

    const size_t baseNeed = 32768 + 2 * (size_t)N_ROWS * K_DIM * 2;      // 67.1 MB
    const size_t partBytes = (size_t)N_ROWS * N_ROWS * 2;                 // 8.39 MB

    int nsplit = 0;
    if (ws_size >= baseNeed + 4 * partBytes) nsplit = 4;
    else if (ws_size >= baseNeed + 2 * partBytes) nsplit = 2;
    else if (ws_size >= baseNeed + 1 * partBytes) nsplit = 1;

    norm_convert<<<dim3(N_ROWS, 2), 256, 0, stream>>>(c_in, a_in, Cbf, Abf,
                                                      invc, inva, accp, counter);
    if (nsplit > 0) {
        gemm_partial8<<<dim3(64, nsplit), 512, 0, stream>>>(Cbf, Abf, simPart,
                                                            K_DIM / nsplit);
        epilogue_loss<<<dim3(N_ROWS / EPI_ROWS), 256, 0, stream>>>(simPart, nsplit, invc, inva,
                                                                   accp, counter, out);
    } else {
        gemm_loss<<<dim3(256), 256, 0, stream>>>(Cbf, Abf, invc, inva, accp);
        finalize<<<1, 64, 0, stream>>>(accp, out);
    }
}